// Round 13
// baseline (253.158 us; speedup 1.0000x reference)
//
#include <hip/hip_runtime.h>

// RWKV time mixing: LN -> token-shift mix -> 3x low-rank proj -> chunked scan
// -> output GEMM. B=4, T=2048, C=2048, R=256.
// Round 13: consolidate to r6-exact GEMM config (measured best 244.5us):
// G1 split-K x2 f32 partials (384 blk), G2 1536 blk, Gout 512 blk, all on the
// ring-3 BK=32 core (0 conflicts, 2 blk/CU). New: lnmix8 -- 8 rows/block with
// 9-row LDS staging kills the 2x re-read of x (134->74 MB).

typedef __attribute__((ext_vector_type(8))) __bf16 bf16x8;
typedef __attribute__((ext_vector_type(4))) float f32x4;

static constexpr int Bb = 4, Tt = 2048, Cc = 2048, Rr = 256;
static constexpr int Mrows = Bb * Tt;      // 8192
static constexpr int NCH = 32, CLEN = 64;  // scan chunking

__device__ __forceinline__ unsigned short f2bf(float f) {
  union { float f; unsigned u; } a; a.f = f;
  unsigned r = (a.u + 0x7FFFu + ((a.u >> 16) & 1u)) >> 16;  // RNE
  return (unsigned short)r;
}
__device__ __forceinline__ float bf2f(unsigned short h) {
  union { unsigned u; float f; } a; a.u = ((unsigned)h) << 16;
  return a.f;
}

__device__ __forceinline__ void gload16(const void* g, void* l) {
  __builtin_amdgcn_global_load_lds(
      (const __attribute__((address_space(1))) void*)g,
      (__attribute__((address_space(3))) void*)l, 16, 0, 0);
}

// ---------------- weight prep (r6 version) ----------------------------------
__global__ void prep_weights(const float* __restrict__ wqa, const float* __restrict__ wka,
                             const float* __restrict__ wva, const float* __restrict__ wqb,
                             const float* __restrict__ wkb, const float* __restrict__ wvb,
                             const float* __restrict__ ow,  const float* __restrict__ td,
                             unsigned short* __restrict__ waT, unsigned short* __restrict__ wbT,
                             unsigned short* __restrict__ owT, float* __restrict__ decay,
                             float* __restrict__ decayL) {
  const int g = blockIdx.x * blockDim.x + threadIdx.x;
  const int stride = gridDim.x * blockDim.x;
  for (int i = g; i < 3 * Rr * Cc; i += stride) {
    int c = i & (Cc - 1); int jj = i >> 11; int p = jj >> 8; int r = jj & (Rr - 1);
    const float* w = (p == 0) ? wqa : ((p == 1) ? wka : wva);
    waT[i] = f2bf(w[(size_t)c * Rr + r]);
  }
  for (int i = g; i < 3 * Cc * Rr; i += stride) {
    int r = i & (Rr - 1); int d = (i >> 8) & (Cc - 1); int p = i >> 19;
    const float* w = (p == 0) ? wqb : ((p == 1) ? wkb : wvb);
    wbT[i] = f2bf(w[(size_t)r * Cc + d]);
  }
  for (int i = g; i < Cc * Cc; i += stride) owT[i] = f2bf(ow[i]);
  for (int i = g; i < Cc; i += stride) {
    float e = expf(td[i]);
    decay[i] = expf(-e);
    decayL[i] = expf(-(float)CLEN * e);
  }
}

// ---------------- LN + token-shift mix, 8 rows per block --------------------
// Block handles output rows m0..m0+7 (m0 = blockIdx.x*8); stages rows
// m0-1..m0+7 (9 x 8KB = 72KB LDS), so each x row is read ~1.125x from HBM.
// Row 8 rows never cross a batch boundary (2048 % 8 == 0); only r=1 can have
// t==0 (when m0%2048==0), in which case prev row is unused.
__global__ __launch_bounds__(256, 2) void lnmix8_kernel(
    const float* __restrict__ x, const float* __restrict__ gamma,
    const float* __restrict__ beta, unsigned short* __restrict__ mix) {
  __shared__ float xs[9][2048];     // 72 KB
  __shared__ float red[9][4][2];
  __shared__ float st[9][2];        // mean, rstd
  const int m0 = blockIdx.x * 8;
  const int t0 = m0 & (Tt - 1);
  const int tid = threadIdx.x;
  const int w = tid >> 6;

  float s[9], q[9];
#pragma unroll
  for (int r = 0; r < 9; ++r) { s[r] = 0.f; q[r] = 0.f; }

  // load rows (skip r=0 when t0==0) + per-thread partials
  for (int r = (t0 == 0 ? 1 : 0); r < 9; ++r) {
    const float* xr = x + (size_t)(m0 - 1 + r) * Cc;
    float4 v0 = ((const float4*)xr)[tid];
    float4 v1 = ((const float4*)xr)[tid + 256];
    ((float4*)xs[r])[tid] = v0;
    ((float4*)xs[r])[tid + 256] = v1;
    s[r] = v0.x + v0.y + v0.z + v0.w + v1.x + v1.y + v1.z + v1.w;
    q[r] = v0.x * v0.x + v0.y * v0.y + v0.z * v0.z + v0.w * v0.w
         + v1.x * v1.x + v1.y * v1.y + v1.z * v1.z + v1.w * v1.w;
  }
  // wave reduce all 9 rows
#pragma unroll
  for (int off = 32; off; off >>= 1) {
#pragma unroll
    for (int r = 0; r < 9; ++r) {
      s[r] += __shfl_down(s[r], off);
      q[r] += __shfl_down(q[r], off);
    }
  }
  if ((tid & 63) == 0) {
#pragma unroll
    for (int r = 0; r < 9; ++r) { red[r][w][0] = s[r]; red[r][w][1] = q[r]; }
  }
  __syncthreads();
  if (tid < 9) {
    float ts = 0.f, tq = 0.f;
#pragma unroll
    for (int wv = 0; wv < 4; ++wv) { ts += red[tid][wv][0]; tq += red[tid][wv][1]; }
    float mu = ts * (1.f / Cc);
    st[tid][0] = mu;
    st[tid][1] = rsqrtf(tq * (1.f / Cc) - mu * mu + 1e-5f);
  }
  __syncthreads();

  const float4 g0 = ((const float4*)gamma)[tid];
  const float4 g1 = ((const float4*)gamma)[tid + 256];
  const float4 b0 = ((const float4*)beta)[tid];
  const float4 b1 = ((const float4*)beta)[tid + 256];

  for (int r = 1; r < 9; ++r) {
    const int m = m0 + r - 1;
    const int t = t0 + r - 1;
    const float mu0 = st[r][0], rs0 = st[r][1];
    float4 c0 = ((const float4*)xs[r])[tid];
    float4 c1 = ((const float4*)xs[r])[tid + 256];
    float ax = (c0.x - mu0) * rs0 * g0.x + b0.x;
    float ay = (c0.y - mu0) * rs0 * g0.y + b0.y;
    float az = (c0.z - mu0) * rs0 * g0.z + b0.z;
    float aw = (c0.w - mu0) * rs0 * g0.w + b0.w;
    float bx = (c1.x - mu0) * rs0 * g1.x + b1.x;
    float by = (c1.y - mu0) * rs0 * g1.y + b1.y;
    float bz = (c1.z - mu0) * rs0 * g1.z + b1.z;
    float bw = (c1.w - mu0) * rs0 * g1.w + b1.w;
    if (t > 0) {
      const float mu1 = st[r - 1][0], rs1 = st[r - 1][1];
      float4 p0 = ((const float4*)xs[r - 1])[tid];
      float4 p1 = ((const float4*)xs[r - 1])[tid + 256];
      ax = 0.5f * (ax + (p0.x - mu1) * rs1 * g0.x + b0.x);
      ay = 0.5f * (ay + (p0.y - mu1) * rs1 * g0.y + b0.y);
      az = 0.5f * (az + (p0.z - mu1) * rs1 * g0.z + b0.z);
      aw = 0.5f * (aw + (p0.w - mu1) * rs1 * g0.w + b0.w);
      bx = 0.5f * (bx + (p1.x - mu1) * rs1 * g1.x + b1.x);
      by = 0.5f * (by + (p1.y - mu1) * rs1 * g1.y + b1.y);
      bz = 0.5f * (bz + (p1.z - mu1) * rs1 * g1.z + b1.z);
      bw = 0.5f * (bw + (p1.w - mu1) * rs1 * g1.w + b1.w);
    } else {
      ax *= 0.5f; ay *= 0.5f; az *= 0.5f; aw *= 0.5f;
      bx *= 0.5f; by *= 0.5f; bz *= 0.5f; bw *= 0.5f;
    }
    ushort4 oa, ob;
    oa.x = f2bf(ax); oa.y = f2bf(ay); oa.z = f2bf(az); oa.w = f2bf(aw);
    ob.x = f2bf(bx); ob.y = f2bf(by); ob.z = f2bf(bz); ob.w = f2bf(bw);
    ((ushort4*)mix)[(size_t)m * 512 + tid] = oa;
    ((ushort4*)mix)[(size_t)m * 512 + tid + 256] = ob;
  }
}

// ---------------- 256x128 BK=32 ring-3 GEMM (r6 core), 2 blocks/CU ----------
// 256 threads = 4 waves (2M x 2N), wave tile 128x64, acc[8][4] f32x4.
// LDS: 3 ring bufs x (A 256x32 16KB + B 128x32 8KB) = 72KB -> 2 blk/CU.
// Swizzle: slot s of row r at s ^ ((r>>1)&3); linear gload_lds dest +
// pre-swizzled global source col + swizzled ds_read (0 conflicts, r3-r12).
// Ring-3: stage(t+2) -> buf whose reads (tile t-1) closed by tile t's top
// barrier; vmcnt(6) gates own stage(t); reads issue BEFORE stage.
template <bool STORE_BF16, bool ADD_BIAS>
__global__ __launch_bounds__(256, 2) void gemm_pipe(
    const unsigned short* __restrict__ A0p, long lda, long aStrideP,
    const unsigned short* __restrict__ B0p, long ldb, long bStrideP,
    void* c0, void* c1, void* c2, void* c3, long ldc, int K,
    const float* __restrict__ bias, int nbx, int nby) {
  __shared__ unsigned short lds[3 * 12288];
  const int tid = threadIdx.x;
  const int nwg = gridDim.x;
  const int id = blockIdx.x;
  const int q = nwg >> 3;
  const int swz = (id & 7) * q + (id >> 3);
  const int per = nbx * nby;
  const int p = swz / per;
  const int r2 = swz - p * per;
  const int mblk = r2 / nbx;
  const int nblk = r2 - mblk * nbx;
  const unsigned short* A  = A0p + (long)p * aStrideP;
  const unsigned short* Bt = B0p + (long)p * bStrideP;
  void* Cout = (p == 0) ? c0 : (p == 1 ? c1 : (p == 2 ? c2 : c3));
  const long m0 = (long)mblk * 256, n0 = (long)nblk * 128;

  const int lane = tid & 63, wid = tid >> 6;
  const int wm = wid >> 1, wn = wid & 1;
  const int fr = lane & 15, fq = lane >> 4;

  const int srow = tid >> 2;
  const int s_src = (tid & 3) ^ ((tid >> 3) & 3);
  const unsigned short* Ag = A + (m0 + srow) * lda + s_src * 8;
  const unsigned short* Bg = Bt + (n0 + srow) * ldb + s_src * 8;

  const int swzs = fq ^ ((fr >> 1) & 3);
  const unsigned short* aBase = &lds[(wm * 128 + fr) * 32 + swzs * 8];
  const unsigned short* bBase = &lds[8192 + (wn * 64 + fr) * 32 + swzs * 8];

  f32x4 acc[8][4];
#pragma unroll
  for (int i = 0; i < 8; ++i)
#pragma unroll
    for (int j = 0; j < 4; ++j) acc[i][j] = (f32x4){0.f, 0.f, 0.f, 0.f};

  const int NT = K >> 5;

  auto stage = [&](int t, int buf) {
    unsigned short* dA = &lds[buf * 12288 + tid * 8];
    unsigned short* dB = &lds[buf * 12288 + 8192 + tid * 8];
    const long kt = (long)t * 32;
#pragma unroll
    for (int l = 0; l < 4; ++l)
      gload16(Ag + (long)(l * 64) * lda + kt, dA + l * 2048);
#pragma unroll
    for (int l = 0; l < 2; ++l)
      gload16(Bg + (long)(l * 64) * ldb + kt, dB + l * 2048);
  };

  stage(0, 0); stage(1, 1);
  int bufR = 0, bufS = 2;

  for (int t = 0; t < NT; ++t) {
    if (t < NT - 1) asm volatile("s_waitcnt vmcnt(6)" ::: "memory");
    else            asm volatile("s_waitcnt vmcnt(0)" ::: "memory");
    __builtin_amdgcn_s_barrier();
    __builtin_amdgcn_sched_barrier(0);

    const unsigned short* ab = aBase + bufR * 12288;
    const unsigned short* bb = bBase + bufR * 12288;

    bf16x8 bf[4], af[8];
#pragma unroll
    for (int j = 0; j < 4; ++j) bf[j] = *(const bf16x8*)(bb + j * 512);
#pragma unroll
    for (int i = 0; i < 8; ++i) af[i] = *(const bf16x8*)(ab + i * 512);
    if (t + 2 < NT) stage(t + 2, bufS);
    __builtin_amdgcn_s_setprio(1);
#pragma unroll
    for (int i = 0; i < 8; ++i)
#pragma unroll
      for (int j = 0; j < 4; ++j)
        acc[i][j] = __builtin_amdgcn_mfma_f32_16x16x32_bf16(af[i], bf[j], acc[i][j], 0, 0, 0);
    __builtin_amdgcn_s_setprio(0);

    bufR = (bufR == 2) ? 0 : bufR + 1;
    bufS = (bufS == 2) ? 0 : bufS + 1;
  }

#pragma unroll
  for (int j = 0; j < 4; ++j) {
    const long col = n0 + wn * 64 + j * 16 + fr;
    const float bv = ADD_BIAS ? bias[col] : 0.0f;
#pragma unroll
    for (int i = 0; i < 8; ++i) {
      const long row0 = m0 + wm * 128 + i * 16 + fq * 4;
#pragma unroll
      for (int r = 0; r < 4; ++r) {
        float val = acc[i][j][r] + bv;
        if (STORE_BF16)
          ((unsigned short*)Cout)[(row0 + r) * ldc + col] = f2bf(val);
        else
          ((float*)Cout)[(row0 + r) * ldc + col] = val;
      }
    }
  }
}

// ---------------- split-K x2 combine for G1 (r6 version) --------------------
__global__ void addcvt_kernel(const float* __restrict__ p0, const float* __restrict__ p1,
                              unsigned short* __restrict__ o, int n4) {
  for (int i = blockIdx.x * blockDim.x + threadIdx.x; i < n4; i += gridDim.x * blockDim.x) {
    float4 a = ((const float4*)p0)[i];
    float4 b = ((const float4*)p1)[i];
    ushort4 r;
    r.x = f2bf(a.x + b.x); r.y = f2bf(a.y + b.y);
    r.z = f2bf(a.z + b.z); r.w = f2bf(a.w + b.w);
    ((ushort4*)o)[i] = r;
  }
}

// ---------------- chunked scan ---------------------------------------------
__global__ void scan_phaseA(const unsigned short* __restrict__ k, const unsigned short* __restrict__ v,
                            const float* __restrict__ decay, float* __restrict__ hend) {
  const int g = blockIdx.x * 256 + threadIdx.x;
  const int c = g & (Cc - 1);
  const int j = (g >> 11) & (NCH - 1);
  const int b = g >> 16;
  const float d = decay[c];
  size_t base = ((size_t)(b * Tt + j * CLEN)) * Cc + c;
  float h = 0.f;
#pragma unroll 8
  for (int s = 0; s < CLEN; ++s) {
    size_t idx = base + (size_t)s * Cc;
    float kv = bf2f(k[idx]) * bf2f(v[idx]);
    h = fmaf(d, h, kv);
  }
  hend[(size_t)(b * NCH + j) * Cc + c] = h;
}

__global__ void scan_combine(const float* __restrict__ hend, const float* __restrict__ h0,
                             const float* __restrict__ decayL, float* __restrict__ Hin,
                             float* __restrict__ hfinal) {
  const int g = blockIdx.x * 256 + threadIdx.x;
  const int c = g & (Cc - 1);
  float H = h0[g];
  const float dl = decayL[c];
  const int b = g >> 11;
  for (int j = 0; j < NCH; ++j) {
    size_t idx = (size_t)(b * NCH + j) * Cc + c;
    Hin[idx] = H;
    H = fmaf(dl, H, hend[idx]);
  }
  hfinal[g] = H;
}

__global__ void scan_phaseB(const unsigned short* __restrict__ q, const unsigned short* __restrict__ k,
                            const unsigned short* __restrict__ v, const float* __restrict__ decay,
                            const float* __restrict__ Hin, unsigned short* __restrict__ ys) {
  const int g = blockIdx.x * 256 + threadIdx.x;
  const int c = g & (Cc - 1);
  const int j = (g >> 11) & (NCH - 1);
  const int b = g >> 16;
  const float d = decay[c];
  float h = Hin[(size_t)(b * NCH + j) * Cc + c];
  size_t base = ((size_t)(b * Tt + j * CLEN)) * Cc + c;
#pragma unroll 4
  for (int s = 0; s < CLEN; ++s) {
    size_t idx = base + (size_t)s * Cc;
    float kv = bf2f(k[idx]) * bf2f(v[idx]);
    h = fmaf(d, h, kv);
    float qq = bf2f(q[idx]);
    float sg = 1.f / (1.f + expf(-qq));
    ys[idx] = f2bf(sg * h);
  }
}

// ---------------- launch ----------------------------------------------------
extern "C" void kernel_launch(void* const* d_in, const int* in_sizes, int n_in,
                              void* d_out, int out_size, void* d_ws, size_t ws_size,
                              hipStream_t stream) {
  const float* x   = (const float*)d_in[0];
  const float* h0  = (const float*)d_in[1];
  const float* gam = (const float*)d_in[2];
  const float* bet = (const float*)d_in[3];
  const float* wqa = (const float*)d_in[4];
  const float* wqb = (const float*)d_in[5];
  const float* wka = (const float*)d_in[6];
  const float* wkb = (const float*)d_in[7];
  const float* wva = (const float*)d_in[8];
  const float* wvb = (const float*)d_in[9];
  const float* ow  = (const float*)d_in[10];
  const float* ob  = (const float*)d_in[11];
  const float* td  = (const float*)d_in[12];
  float* out = (float*)d_out;

  char* ws = (char*)d_ws;
  unsigned short* waT   = (unsigned short*)(ws + 0);          //  3,145,728
  unsigned short* wbT   = (unsigned short*)(ws + 3145728);    //  3,145,728
  unsigned short* owT   = (unsigned short*)(ws + 6291456);    //  8,388,608
  float*          decay = (float*)(ws + 14680064);
  float*          decayL= (float*)(ws + 14688256);
  unsigned short* mixb  = (unsigned short*)(ws + 14761984);   // 33,554,432 (reused as ys)
  unsigned short* tmp   = (unsigned short*)(ws + 48316416);   // 12,582,912
  unsigned short* vp    = (unsigned short*)(ws + 60899328);   // 33,554,432
  float*          hend  = (float*)(ws + 94453760);
  float*          Hin   = (float*)(ws + 95502336);
  // staged in d_out (dead before overwritten): G1 f32 partials, then q,k bf16
  float* P0 = (float*)d_out;                                  // 25.2 MB
  float* P1 = P0 + (size_t)Mrows * 768;                       // 25.2 MB
  unsigned short* qp = (unsigned short*)d_out;
  unsigned short* kp = qp + (size_t)Mrows * Cc;
  float* hfinal = out + (size_t)Mrows * Cc;
  unsigned short* ysb = mixb;

  prep_weights<<<1024, 256, 0, stream>>>(wqa, wka, wva, wqb, wkb, wvb, ow, td,
                                         waT, wbT, owT, decay, decayL);
  lnmix8_kernel<<<Mrows / 8, 256, 0, stream>>>(x, gam, bet, mixb);

  // G1 split-K x2 (grid p): P_p = mix[:, p*1024:(p+1)*1024] @ waT_half
  // 384 blocks = 2p x (nbx=6 x nby=32); K=1024, f32 partials (r6 config)
  gemm_pipe<false, false><<<384, 256, 0, stream>>>(
      mixb, Cc, 1024, waT, Cc, 1024,
      P0, P1, nullptr, nullptr, 768, 1024, nullptr, 6, 32);
  addcvt_kernel<<<1024, 256, 0, stream>>>(P0, P1, tmp, Mrows * 768 / 4);

  // G2 (r6 config): q/k/v = tmp_p @ w_b_p; 1536 blocks, K=256
  gemm_pipe<true, false><<<1536, 256, 0, stream>>>(
      tmp, 768, 256, wbT, Rr, (long)Cc * Rr,
      qp, kp, vp, nullptr, Cc, 256, nullptr, 16, 32);

  scan_phaseA<<<(Bb * NCH * Cc) / 256, 256, 0, stream>>>(kp, vp, decay, hend);
  scan_combine<<<(Bb * Cc) / 256, 256, 0, stream>>>(hend, h0, decayL, Hin, hfinal);
  scan_phaseB<<<(Bb * NCH * Cc) / 256, 256, 0, stream>>>(qp, kp, vp, decay, Hin, ysb);

  // Gout (r6 config): out = ys @ out_w^T + out_b; 512 blocks, K=2048
  gemm_pipe<false, true><<<512, 256, 0, stream>>>(
      ysb, Cc, 0, owT, Cc, 0,
      out, out, out, nullptr, Cc, 2048, ob, 16, 32);
}